// Round 12
// baseline (75.945 us; speedup 1.0000x reference)
//
#include <hip/hip_runtime.h>

#define NSTATE 128
#define NM1    127
#define UDIM   4
#define CHUNK  1024
#define BLOCKT 256

typedef float v4f __attribute__((ext_vector_type(4)));

// R12: R11 chunk-local bucketing, scaled up.
//  - CHUNK 512 -> 1024: avg bucket 8 rows; per-bucket operand loads (2.5KB)
//    amortize 2x better (320B/row); bucket-loop overhead halves.
//  - Inner loop processes TWO pairs (4 rows) per iteration: two independent
//    exp/butterfly/log chains interleaved, next two pairs' row-ids + u
//    prefetched before the stores.
// Row mapping: lanes 0-31 = row A of pair, lanes 32-63 = row B; lane owns 4
// cols -> one nt wave-store = 2 complete rows (8 full 128B lines).
// No-max softmax validated R2-R11 (absmax 0.0625 vs thr 0.186).

__device__ __forceinline__ float dot4(const float4 a, const float4 b) {
    return fmaf(a.x, b.x, fmaf(a.y, b.y, fmaf(a.z, b.z, a.w * b.w)));
}

// ---------------- pre-pass: de-interleaved padded weight table (R8) ----------------
__global__ __launch_bounds__(128) void k_build_wt(
    const float* __restrict__ W, float4* __restrict__ Wt)
{
    const int s = blockIdx.x;      // 0..127
    const int j = threadIdx.x;     // 0..127
    float4 v = make_float4(0.0f, 0.0f, 0.0f, 0.0f);
    if (j != s) {
        const int k = j - (j > s);
        v = *reinterpret_cast<const float4*>(W + ((size_t)s * NM1 + k) * UDIM);
    }
    Wt[(((j & 1) * NSTATE + s) << 6) + (j >> 1)] = v;
}

// ---------------- hot kernel ----------------
__global__ __launch_bounds__(256) void k_chunked(
    const int*    __restrict__ x_curr,
    const float*  __restrict__ u_curr,
    const float*  __restrict__ logP0,
    const float4* __restrict__ Wt,
    float*        __restrict__ out,
    int T)
{
    __shared__ int cnt[NSTATE], basep[NSTATE], off[NSTATE];
    __shared__ int sa[NSTATE], sb[NSTATE];
    __shared__ unsigned short list[CHUNK];

    const int tid    = threadIdx.x;
    const int chunk0 = blockIdx.x * CHUNK;
    const int cend   = (T - chunk0 < CHUNK) ? (T - chunk0) : CHUNK;

    if (tid < NSTATE) { cnt[tid] = 0; off[tid] = 0; }
    __syncthreads();

    // ---- phase 1a: count ----
    int xloc[CHUNK / BLOCKT];
    #pragma unroll
    for (int c = 0; c < CHUNK / BLOCKT; ++c) {
        const int i = tid + c * BLOCKT;
        xloc[c] = (i < cend) ? x_curr[chunk0 + i] : -1;
        if (xloc[c] >= 0) atomicAdd(&cnt[xloc[c]], 1);
    }
    __syncthreads();

    // ---- phase 1b: exclusive scan over 128 bins ----
    if (tid < NSTATE) sa[tid] = cnt[tid];
    __syncthreads();
    {
        int* src = sa; int* dst = sb;
        #pragma unroll
        for (int o = 1; o < NSTATE; o <<= 1) {
            if (tid < NSTATE) dst[tid] = (tid >= o) ? (src[tid] + src[tid - o]) : src[tid];
            __syncthreads();
            int* tmp = src; src = dst; dst = tmp;
        }
        if (tid < NSTATE) basep[tid] = src[tid] - cnt[tid];
    }
    __syncthreads();

    // ---- phase 1c: place ----
    #pragma unroll
    for (int c = 0; c < CHUNK / BLOCKT; ++c) {
        const int i = tid + c * BLOCKT;
        if (xloc[c] >= 0) {
            const int p = basep[xloc[c]] + atomicAdd(&off[xloc[c]], 1);
            list[p] = (unsigned short)i;
        }
    }
    __syncthreads();

    // ---- phase 2: per-bucket compute, 2 pairs (4 rows) per iteration ----
    const int lane = tid & 63;
    const int wv   = tid >> 6;      // 0..3
    const int h    = lane >> 5;     // half: 0 = row A of pair, 1 = row B
    const int lh   = lane & 31;     // lane within half
    const int j0   = 4 * lh;        // this lane's 4 columns

    for (int s = wv; s < NSTATE; s += 4) {
        const int n = cnt[s];
        if (n == 0) continue;
        const int b = basep[s];

        // per-bucket operands (loaded once)
        const float4 wA = Wt[(s << 6) + 2 * lh];
        const float4 wB = Wt[((NSTATE + s) << 6) + 2 * lh];
        const float4 wC = Wt[(s << 6) + 2 * lh + 1];
        const float4 wD = Wt[((NSTATE + s) << 6) + 2 * lh + 1];
        const float4 lp = *reinterpret_cast<const float4*>(logP0 + s * NSTATE + j0);

        const int npair = (n + 1) >> 1;

        // row id for (pair q, half h), clamped to bucket end (duplicates benign:
        // both halves then write identical bytes to identical addresses)
        auto pr = [&](int q) -> int {
            int e = 2 * q + h;
            if (e >= n) e = n - 1;
            return chunk0 + list[b + e];
        };
        auto ldu = [&](int r) {
            return *reinterpret_cast<const float4*>(u_curr + (size_t)r * UDIM);
        };

        int    rP = pr(0);          float4 uP = ldu(rP);
        int    rQ = pr(1);          float4 uQ = ldu(rQ);   // clamped if npair==1

        for (int p = 0; p < npair; p += 2) {
            // prefetch pairs p+2, p+3
            int rPn = rP, rQn = rQ; float4 uPn = uP, uQn = uQ;
            if (p + 2 < npair) { rPn = pr(p + 2); uPn = ldu(rPn); }
            if (p + 3 < npair) { rQn = pr(p + 3); uQn = ldu(rQn); }

            // pair p logits
            const float a0 = lp.x + dot4(uP, wA);
            const float a1 = lp.y + dot4(uP, wB);
            const float a2 = lp.z + dot4(uP, wC);
            const float a3 = lp.w + dot4(uP, wD);
            // pair p+1 logits
            const float b0 = lp.x + dot4(uQ, wA);
            const float b1 = lp.y + dot4(uQ, wB);
            const float b2 = lp.z + dot4(uQ, wC);
            const float b3 = lp.w + dot4(uQ, wD);

            float eP = (__expf(a0) + __expf(a1)) + (__expf(a2) + __expf(a3));
            float eQ = (__expf(b0) + __expf(b1)) + (__expf(b2) + __expf(b3));
            #pragma unroll
            for (int o = 16; o >= 1; o >>= 1) {
                eP += __shfl_xor(eP, o, 64);    // within 32-lane half
                eQ += __shfl_xor(eQ, o, 64);
            }
            const float lP = __logf(eP);
            const float lQ = __logf(eQ);

            v4f oP;
            oP[0] = a0 - lP; oP[1] = a1 - lP; oP[2] = a2 - lP; oP[3] = a3 - lP;
            __builtin_nontemporal_store(
                oP, reinterpret_cast<v4f*>(out + (size_t)rP * NSTATE + j0));
            if (p + 1 < npair) {
                v4f oQ;
                oQ[0] = b0 - lQ; oQ[1] = b1 - lQ; oQ[2] = b2 - lQ; oQ[3] = b3 - lQ;
                __builtin_nontemporal_store(
                    oQ, reinterpret_cast<v4f*>(out + (size_t)rQ * NSTATE + j0));
            }

            rP = rPn; uP = uPn; rQ = rQn; uQ = uQn;
        }
    }
}

// ---------------- fallback (ws too small): R8-style direct kernel ----------------
__global__ __launch_bounds__(256) void k_fallback(
    const int* __restrict__ x_curr, const float* __restrict__ u_curr,
    const float* __restrict__ logP0, const float* __restrict__ W,
    float* __restrict__ out, int T)
{
    const int lane    = threadIdx.x & 63;
    const int wave_id = (blockIdx.x * blockDim.x + threadIdx.x) >> 6;
    const int nwaves  = (gridDim.x * blockDim.x) >> 6;
    const int j0 = 2 * lane, j1 = j0 + 1;
    for (int t = wave_id; t < T; t += nwaves) {
        int s = x_curr[t];
        s = __builtin_amdgcn_readfirstlane(s);
        const float4 uv = *reinterpret_cast<const float4*>(u_curr + (size_t)t * UDIM);
        float st0 = 0.0f, st1 = 0.0f;
        if (j0 != s) {
            const int k = j0 - (j0 > s);
            const float4 w = *reinterpret_cast<const float4*>(W + ((size_t)s * NM1 + k) * UDIM);
            st0 = dot4(uv, w);
        }
        if (j1 != s) {
            const int k = j1 - (j1 > s);
            const float4 w = *reinterpret_cast<const float4*>(W + ((size_t)s * NM1 + k) * UDIM);
            st1 = dot4(uv, w);
        }
        const float2 lp = *reinterpret_cast<const float2*>(logP0 + (size_t)s * NSTATE + j0);
        const float v0 = lp.x + st0, v1 = lp.y + st1;
        float e = __expf(v0) + __expf(v1);
        #pragma unroll
        for (int o = 32; o >= 1; o >>= 1)
            e += __shfl_xor(e, o, 64);
        const float l = __logf(e);
        float2 o2; o2.x = v0 - l; o2.y = v1 - l;
        *reinterpret_cast<float2*>(out + (size_t)t * NSTATE + j0) = o2;
    }
}

extern "C" void kernel_launch(void* const* d_in, const int* in_sizes, int n_in,
                              void* d_out, int out_size, void* d_ws, size_t ws_size,
                              hipStream_t stream) {
    const int*   x_curr = (const int*)  d_in[0];
    const float* u_curr = (const float*)d_in[1];
    const float* logP0  = (const float*)d_in[2];
    const float* W      = (const float*)d_in[3];
    float*       out    = (float*)d_out;

    const int T = in_sizes[0];
    const size_t need = (size_t)2 * NSTATE * 64 * sizeof(float4);  // 256 KB

    if (ws_size < need) {
        hipLaunchKernelGGL(k_fallback, dim3(2048), dim3(256), 0, stream,
                           x_curr, u_curr, logP0, W, out, T);
        return;
    }

    float4* Wt = (float4*)d_ws;
    hipLaunchKernelGGL(k_build_wt, dim3(NSTATE), dim3(NSTATE), 0, stream, W, Wt);

    const int nblk = (T + CHUNK - 1) / CHUNK;   // 489 blocks at T=500K
    hipLaunchKernelGGL(k_chunked, dim3(nblk), dim3(BLOCKT), 0, stream,
                       x_curr, u_curr, logP0, Wt, out, T);
}

// Round 13
// 72.787 us; speedup vs baseline: 1.0434x; 1.0434x over previous
//
#include <hip/hip_runtime.h>

#define NSTATE 128
#define NM1    127
#define UDIM   4
#define CHUNK  512
#define BLOCKT 512

typedef float v4f __attribute__((ext_vector_type(4)));

// R13: exact R11 structure (CHUNK=512 chunk-local bucketing, 2 rows/wave,
// per-bucket operand reuse, nt wave-stores) with ONE change: BLOCKT 256->512
// (8 waves/block, wave wv handles states s = wv mod 8). ~30 waves/CU instead
// of ~15: doubles the independent dot->exp->butterfly->log chains in flight
// per SIMD. Traffic, bucket sizes, and write locality identical to R11.
// No-max softmax validated R2-R12 (absmax 0.0625 vs thr 0.186).

__device__ __forceinline__ float dot4(const float4 a, const float4 b) {
    return fmaf(a.x, b.x, fmaf(a.y, b.y, fmaf(a.z, b.z, a.w * b.w)));
}

// ---------------- pre-pass: de-interleaved padded weight table (R8) ----------------
__global__ __launch_bounds__(128) void k_build_wt(
    const float* __restrict__ W, float4* __restrict__ Wt)
{
    const int s = blockIdx.x;      // 0..127
    const int j = threadIdx.x;     // 0..127
    float4 v = make_float4(0.0f, 0.0f, 0.0f, 0.0f);
    if (j != s) {
        const int k = j - (j > s);
        v = *reinterpret_cast<const float4*>(W + ((size_t)s * NM1 + k) * UDIM);
    }
    Wt[(((j & 1) * NSTATE + s) << 6) + (j >> 1)] = v;
}

// ---------------- hot kernel ----------------
__global__ __launch_bounds__(512) void k_chunked(
    const int*    __restrict__ x_curr,
    const float*  __restrict__ u_curr,
    const float*  __restrict__ logP0,
    const float4* __restrict__ Wt,
    float*        __restrict__ out,
    int T)
{
    __shared__ int cnt[NSTATE], basep[NSTATE], off[NSTATE];
    __shared__ int sa[NSTATE], sb[NSTATE];
    __shared__ unsigned short list[CHUNK];

    const int tid    = threadIdx.x;
    const int chunk0 = blockIdx.x * CHUNK;
    const int cend   = (T - chunk0 < CHUNK) ? (T - chunk0) : CHUNK;

    if (tid < NSTATE) { cnt[tid] = 0; off[tid] = 0; }
    __syncthreads();

    // ---- phase 1a: count (1 row per thread) ----
    int xloc = (tid < cend) ? x_curr[chunk0 + tid] : -1;
    if (xloc >= 0) atomicAdd(&cnt[xloc], 1);
    __syncthreads();

    // ---- phase 1b: exclusive scan over 128 bins ----
    if (tid < NSTATE) sa[tid] = cnt[tid];
    __syncthreads();
    {
        int* src = sa; int* dst = sb;
        #pragma unroll
        for (int o = 1; o < NSTATE; o <<= 1) {
            if (tid < NSTATE) dst[tid] = (tid >= o) ? (src[tid] + src[tid - o]) : src[tid];
            __syncthreads();
            int* tmp = src; src = dst; dst = tmp;
        }
        if (tid < NSTATE) basep[tid] = src[tid] - cnt[tid];
    }
    __syncthreads();

    // ---- phase 1c: place ----
    if (xloc >= 0) {
        const int p = basep[xloc] + atomicAdd(&off[xloc], 1);
        list[p] = (unsigned short)tid;
    }
    __syncthreads();

    // ---- phase 2: per-bucket compute, 2 rows per wave ----
    const int lane = tid & 63;
    const int wv   = tid >> 6;      // 0..7
    const int h    = lane >> 5;     // half: 0 = row A, 1 = row B
    const int lh   = lane & 31;     // lane within half
    const int j0   = 4 * lh;        // this lane's 4 columns

    for (int s = wv; s < NSTATE; s += 8) {
        const int n = cnt[s];
        if (n == 0) continue;
        const int b = basep[s];

        // per-bucket operands (loaded once; halves broadcast-share lines)
        const float4 wA = Wt[(s << 6) + 2 * lh];                 // col 4lh
        const float4 wB = Wt[((NSTATE + s) << 6) + 2 * lh];      // col 4lh+1
        const float4 wC = Wt[(s << 6) + 2 * lh + 1];             // col 4lh+2
        const float4 wD = Wt[((NSTATE + s) << 6) + 2 * lh + 1];  // col 4lh+3
        const float4 lp = *reinterpret_cast<const float4*>(logP0 + s * NSTATE + j0);

        const int npair = (n + 1) >> 1;

        // first pair (odd n duplicates row A in half B: identical bytes twice)
        int rA0 = chunk0 + list[b];
        int rB0 = (n > 1) ? (chunk0 + list[b + 1]) : rA0;
        int r   = h ? rB0 : rA0;
        float4 uv = *reinterpret_cast<const float4*>(u_curr + (size_t)r * UDIM);

        for (int p = 0; p < npair; ++p) {
            // prefetch next pair's row id + u
            int rn = r; float4 un = uv;
            if (p + 1 < npair) {
                const int e0 = b + 2 * (p + 1);
                const int nA = chunk0 + list[e0];
                const int nB = (2 * (p + 1) + 1 < n) ? (chunk0 + list[e0 + 1]) : nA;
                rn = h ? nB : nA;
                un = *reinterpret_cast<const float4*>(u_curr + (size_t)rn * UDIM);
            }

            const float v0 = lp.x + dot4(uv, wA);
            const float v1 = lp.y + dot4(uv, wB);
            const float v2 = lp.z + dot4(uv, wC);
            const float v3 = lp.w + dot4(uv, wD);

            float e = (__expf(v0) + __expf(v1)) + (__expf(v2) + __expf(v3));
            #pragma unroll
            for (int o = 16; o >= 1; o >>= 1)
                e += __shfl_xor(e, o, 64);      // stays within 32-lane half
            const float l = __logf(e);

            v4f ov;
            ov[0] = v0 - l; ov[1] = v1 - l; ov[2] = v2 - l; ov[3] = v3 - l;
            __builtin_nontemporal_store(
                ov, reinterpret_cast<v4f*>(out + (size_t)r * NSTATE + j0));

            r = rn; uv = un;
        }
    }
}

// ---------------- fallback (ws too small): R8-style direct kernel ----------------
__global__ __launch_bounds__(256) void k_fallback(
    const int* __restrict__ x_curr, const float* __restrict__ u_curr,
    const float* __restrict__ logP0, const float* __restrict__ W,
    float* __restrict__ out, int T)
{
    const int lane    = threadIdx.x & 63;
    const int wave_id = (blockIdx.x * blockDim.x + threadIdx.x) >> 6;
    const int nwaves  = (gridDim.x * blockDim.x) >> 6;
    const int j0 = 2 * lane, j1 = j0 + 1;
    for (int t = wave_id; t < T; t += nwaves) {
        int s = x_curr[t];
        s = __builtin_amdgcn_readfirstlane(s);
        const float4 uv = *reinterpret_cast<const float4*>(u_curr + (size_t)t * UDIM);
        float st0 = 0.0f, st1 = 0.0f;
        if (j0 != s) {
            const int k = j0 - (j0 > s);
            const float4 w = *reinterpret_cast<const float4*>(W + ((size_t)s * NM1 + k) * UDIM);
            st0 = dot4(uv, w);
        }
        if (j1 != s) {
            const int k = j1 - (j1 > s);
            const float4 w = *reinterpret_cast<const float4*>(W + ((size_t)s * NM1 + k) * UDIM);
            st1 = dot4(uv, w);
        }
        const float2 lp = *reinterpret_cast<const float2*>(logP0 + (size_t)s * NSTATE + j0);
        const float v0 = lp.x + st0, v1 = lp.y + st1;
        float e = __expf(v0) + __expf(v1);
        #pragma unroll
        for (int o = 32; o >= 1; o >>= 1)
            e += __shfl_xor(e, o, 64);
        const float l = __logf(e);
        float2 o2; o2.x = v0 - l; o2.y = v1 - l;
        *reinterpret_cast<float2*>(out + (size_t)t * NSTATE + j0) = o2;
    }
}

extern "C" void kernel_launch(void* const* d_in, const int* in_sizes, int n_in,
                              void* d_out, int out_size, void* d_ws, size_t ws_size,
                              hipStream_t stream) {
    const int*   x_curr = (const int*)  d_in[0];
    const float* u_curr = (const float*)d_in[1];
    const float* logP0  = (const float*)d_in[2];
    const float* W      = (const float*)d_in[3];
    float*       out    = (float*)d_out;

    const int T = in_sizes[0];
    const size_t need = (size_t)2 * NSTATE * 64 * sizeof(float4);  // 256 KB

    if (ws_size < need) {
        hipLaunchKernelGGL(k_fallback, dim3(2048), dim3(256), 0, stream,
                           x_curr, u_curr, logP0, W, out, T);
        return;
    }

    float4* Wt = (float4*)d_ws;
    hipLaunchKernelGGL(k_build_wt, dim3(NSTATE), dim3(NSTATE), 0, stream, W, Wt);

    const int nblk = (T + CHUNK - 1) / CHUNK;   // 977 blocks at T=500K
    hipLaunchKernelGGL(k_chunked, dim3(nblk), dim3(BLOCKT), 0, stream,
                       x_curr, u_curr, logP0, Wt, out, T);
}

// Round 14
// 65.392 us; speedup vs baseline: 1.1614x; 1.1131x over previous
//
#include <hip/hip_runtime.h>

#define NSTATE 128
#define NM1    127
#define UDIM   4

typedef float v4f  __attribute__((ext_vector_type(4)));
typedef _Float16 h2 __attribute__((ext_vector_type(2)));

// R14: LDS-resident fp16 weight table + sequential row mapping.
// Pre-pass packs padded de-interleaved W (self col = 0) into fp16: 128 states
// x 128 cols x 4 dims x 2B = 128KB, laid out per state as 64 uint4:
//   col j -> lane lh=j>>2, unit=(j>>1)&1, slot=j&1
//   byte off = s*1024 + unit*512 + lh*16 + slot*8
// Hot kernel (1024 thr, 128KB static LDS, 1 block/CU, 16 waves): copy table
// to LDS once, then walk a CONTIGUOUS span of row-pairs: lanes 0-31 = row 2p,
// lanes 32-63 = row 2p+1, lane owns 4 cols. w from LDS (2x ds_read_b128,
// conflict-free: 32 lanes x stride 16B), dot via v_dot2_f32_f16, no-max
// softmax (validated R2-R13), one 1KB contiguous nt-store per wave.
// Block's stores sweep its span sequentially -> DRAM page locality like
// fillBuffer (which hits 7 TB/s at 3.5 waves/CU).
// Reads/row: 4B x + 16B u (both sequential) + 512B lp (L2-resident 64KB).
// fp16 w/u: stim err ~2e-4 (w~0.01 scale), far under thr 0.186.

__device__ __forceinline__ h2 as_h2(unsigned v) {
    union { unsigned u; h2 h; } c; c.u = v; return c.h;
}

__device__ __forceinline__ float dot2x2(unsigned wlo, unsigned whi, h2 u01, h2 u23) {
#if __has_builtin(__builtin_amdgcn_fdot2)
    return __builtin_amdgcn_fdot2(as_h2(wlo), u01,
           __builtin_amdgcn_fdot2(as_h2(whi), u23, 0.0f, false), false);
#else
    h2 a = as_h2(wlo), b = as_h2(whi);
    return (float)a[0] * (float)u01[0] + (float)a[1] * (float)u01[1]
         + (float)b[0] * (float)u23[0] + (float)b[1] * (float)u23[1];
#endif
}

// ---------------- pre-pass: pack fp16 table into ws ----------------
__global__ __launch_bounds__(128) void k_build_wh(
    const float* __restrict__ W, char* __restrict__ Wh)
{
    const int s = blockIdx.x;     // 0..127
    const int j = threadIdx.x;    // 0..127
    float4 w = make_float4(0.0f, 0.0f, 0.0f, 0.0f);
    if (j != s) {
        const int k = j - (j > s);
        w = *reinterpret_cast<const float4*>(W + ((size_t)s * NM1 + k) * UDIM);
    }
    h2 a; a[0] = (_Float16)w.x; a[1] = (_Float16)w.y;
    h2 b; b[0] = (_Float16)w.z; b[1] = (_Float16)w.w;
    const size_t off = (size_t)s * 1024 + (size_t)((j >> 1) & 1) * 512
                     + (size_t)(j >> 2) * 16 + (size_t)(j & 1) * 8;
    *reinterpret_cast<h2*>(Wh + off)     = a;
    *reinterpret_cast<h2*>(Wh + off + 4) = b;
}

// ---------------- hot kernel ----------------
__global__ __launch_bounds__(1024) void k_seq(
    const int*   __restrict__ x_curr,
    const float* __restrict__ u_curr,
    const float* __restrict__ logP0,
    const uint4* __restrict__ Wh,
    float*       __restrict__ out,
    int T, int pairs_per_block)
{
    __shared__ uint4 wt[8192];    // 128 KB

    const int tid = threadIdx.x;
    #pragma unroll
    for (int i = 0; i < 8; ++i)
        wt[tid + i * 1024] = Wh[tid + i * 1024];
    __syncthreads();

    const int lane = tid & 63;
    const int wv   = tid >> 6;      // 0..15
    const int h    = lane >> 5;     // 0 = row 2p, 1 = row 2p+1
    const int lh   = lane & 31;
    const int j0   = 4 * lh;

    const int npairs = (T + 1) >> 1;
    const int pair0  = blockIdx.x * pairs_per_block;
    const int pairN  = (pair0 + pairs_per_block < npairs) ? (pair0 + pairs_per_block) : npairs;

    for (int p = pair0 + wv; p < pairN; p += 16) {
        const int r0 = 2 * p;
        const int r1 = (r0 + 1 < T) ? (r0 + 1) : r0;   // odd-T clamp (benign dup)

        int s0 = x_curr[r0], s1 = x_curr[r1];
        s0 = __builtin_amdgcn_readfirstlane(s0);
        s1 = __builtin_amdgcn_readfirstlane(s1);
        const int s = h ? s1 : s0;
        const int r = h ? r1 : r0;

        const float4 uv = *reinterpret_cast<const float4*>(u_curr + (size_t)r * UDIM);
        h2 u01; u01[0] = (_Float16)uv.x; u01[1] = (_Float16)uv.y;
        h2 u23; u23[0] = (_Float16)uv.z; u23[1] = (_Float16)uv.w;

        // cols 4lh,4lh+1 in w0; cols 4lh+2,4lh+3 in w1 (conflict-free b128)
        const uint4 w0 = wt[s * 64 + lh];
        const uint4 w1 = wt[s * 64 + 32 + lh];

        const float4 lp = *reinterpret_cast<const float4*>(logP0 + (size_t)s * NSTATE + j0);

        const float v0 = lp.x + dot2x2(w0.x, w0.y, u01, u23);
        const float v1 = lp.y + dot2x2(w0.z, w0.w, u01, u23);
        const float v2 = lp.z + dot2x2(w1.x, w1.y, u01, u23);
        const float v3 = lp.w + dot2x2(w1.z, w1.w, u01, u23);

        float e = (__expf(v0) + __expf(v1)) + (__expf(v2) + __expf(v3));
        #pragma unroll
        for (int o = 16; o >= 1; o >>= 1)
            e += __shfl_xor(e, o, 64);      // within 32-lane half
        const float l = __logf(e);

        v4f ov;
        ov[0] = v0 - l; ov[1] = v1 - l; ov[2] = v2 - l; ov[3] = v3 - l;
        __builtin_nontemporal_store(
            ov, reinterpret_cast<v4f*>(out + (size_t)r * NSTATE + j0));
    }
}

// ---------------- fallback (ws too small): R8-style direct kernel ----------------
__device__ __forceinline__ float dot4(const float4 a, const float4 b) {
    return fmaf(a.x, b.x, fmaf(a.y, b.y, fmaf(a.z, b.z, a.w * b.w)));
}

__global__ __launch_bounds__(256) void k_fallback(
    const int* __restrict__ x_curr, const float* __restrict__ u_curr,
    const float* __restrict__ logP0, const float* __restrict__ W,
    float* __restrict__ out, int T)
{
    const int lane    = threadIdx.x & 63;
    const int wave_id = (blockIdx.x * blockDim.x + threadIdx.x) >> 6;
    const int nwaves  = (gridDim.x * blockDim.x) >> 6;
    const int j0 = 2 * lane, j1 = j0 + 1;
    for (int t = wave_id; t < T; t += nwaves) {
        int s = x_curr[t];
        s = __builtin_amdgcn_readfirstlane(s);
        const float4 uv = *reinterpret_cast<const float4*>(u_curr + (size_t)t * UDIM);
        float st0 = 0.0f, st1 = 0.0f;
        if (j0 != s) {
            const int k = j0 - (j0 > s);
            const float4 w = *reinterpret_cast<const float4*>(W + ((size_t)s * NM1 + k) * UDIM);
            st0 = dot4(uv, w);
        }
        if (j1 != s) {
            const int k = j1 - (j1 > s);
            const float4 w = *reinterpret_cast<const float4*>(W + ((size_t)s * NM1 + k) * UDIM);
            st1 = dot4(uv, w);
        }
        const float2 lp = *reinterpret_cast<const float2*>(logP0 + (size_t)s * NSTATE + j0);
        const float v0 = lp.x + st0, v1 = lp.y + st1;
        float e = __expf(v0) + __expf(v1);
        #pragma unroll
        for (int o = 32; o >= 1; o >>= 1)
            e += __shfl_xor(e, o, 64);
        const float l = __logf(e);
        float2 o2; o2.x = v0 - l; o2.y = v1 - l;
        *reinterpret_cast<float2*>(out + (size_t)t * NSTATE + j0) = o2;
    }
}

extern "C" void kernel_launch(void* const* d_in, const int* in_sizes, int n_in,
                              void* d_out, int out_size, void* d_ws, size_t ws_size,
                              hipStream_t stream) {
    const int*   x_curr = (const int*)  d_in[0];
    const float* u_curr = (const float*)d_in[1];
    const float* logP0  = (const float*)d_in[2];
    const float* W      = (const float*)d_in[3];
    float*       out    = (float*)d_out;

    const int T = in_sizes[0];
    const size_t need = 131072;   // 128 KB fp16 table

    if (ws_size < need || T < 2) {
        hipLaunchKernelGGL(k_fallback, dim3(2048), dim3(256), 0, stream,
                           x_curr, u_curr, logP0, W, out, T);
        return;
    }

    hipLaunchKernelGGL(k_build_wh, dim3(NSTATE), dim3(NSTATE), 0, stream,
                       W, (char*)d_ws);

    const int npairs = (T + 1) >> 1;
    const int nblk   = 256;                            // 1 block/CU (128KB LDS)
    const int ppb    = (npairs + nblk - 1) / nblk;     // contiguous pair span
    hipLaunchKernelGGL(k_seq, dim3(nblk), dim3(1024), 0, stream,
                       x_curr, u_curr, logP0, (const uint4*)d_ws, out, T, ppb);
}